// Round 1
// baseline (95.466 us; speedup 1.0000x reference)
//
#include <hip/hip_runtime.h>
#include <hip/hip_bf16.h>
#include <stdint.h>

#define NROWS 65536
#define KMIX 64
#define DD 64
#define ZS 65          // z row stride (u + 64 x)
#define CHUNK 128      // rows per k_main block; buckets padded to multiple of this
#define PADN (NROWS + KMIX * CHUNK)
#define NBLK4 (PADN / CHUNK)   // 576

typedef __bf16 bf16x8 __attribute__((ext_vector_type(8)));
typedef float f32x4 __attribute__((ext_vector_type(4)));

// fp32 -> bf16 bits, round-to-nearest-even (inputs finite)
__device__ __forceinline__ unsigned short f2bf(float f) {
  unsigned int x = __float_as_uint(f);
  unsigned int r = (x + 0x7FFFu + ((x >> 16) & 1u)) >> 16;
  return (unsigned short)r;
}

// ---------- K1: idx per row + per-block histogram ----------
__global__ __launch_bounds__(256) void k_idx(
    const float* __restrict__ z, const float* __restrict__ mix,
    uint32_t* __restrict__ idx_arr, uint32_t* __restrict__ bh) {
  __shared__ float s_mix[KMIX];
  __shared__ uint32_t s_hist[KMIX];
  int t = threadIdx.x;
  if (t < KMIX) { s_mix[t] = mix[t]; s_hist[t] = 0u; }
  __syncthreads();
  int n = blockIdx.x * 256 + t;          // grid is exactly NROWS threads
  float u = z[n * ZS];
  int idx = 0;
  #pragma unroll
  for (int k = 0; k < KMIX; ++k) idx += (s_mix[k] <= u) ? 1 : 0;  // side='right'
  if (idx > KMIX - 1) idx = KMIX - 1;
  idx_arr[n] = (uint32_t)idx;
  atomicAdd(&s_hist[idx], 1u);
  __syncthreads();
  if (t < KMIX) bh[blockIdx.x * KMIX + t] = s_hist[t];
}

// ---------- K2: reduce histograms, padded exclusive scan ----------
__global__ void k_scan(const uint32_t* __restrict__ bh,
                       uint32_t* __restrict__ counts,
                       uint32_t* __restrict__ offsets,
                       uint32_t* __restrict__ cursors) {
  __shared__ uint32_t s_c[KMIX];
  int t = threadIdx.x;   // 64 threads
  uint32_t c = 0;
  for (int b = 0; b < NROWS / 256; ++b) c += bh[b * KMIX + t];
  s_c[t] = c;
  counts[t] = c;
  __syncthreads();
  if (t == 0) {
    uint32_t off = 0;
    for (int k = 0; k < KMIX; ++k) {
      offsets[k] = off;
      cursors[k] = off;
      off += ((s_c[k] + CHUNK - 1) / CHUNK) * CHUNK;
    }
    offsets[KMIX] = off;
  }
}

// ---------- K3: scatter row ids into bucket segments ----------
__global__ __launch_bounds__(256) void k_scatter(
    const uint32_t* __restrict__ idx_arr,
    uint32_t* __restrict__ cursors, uint32_t* __restrict__ sorted) {
  __shared__ uint32_t h[KMIX];
  __shared__ uint32_t base[KMIX];
  int t = threadIdx.x;
  if (t < KMIX) h[t] = 0u;
  __syncthreads();
  int n = blockIdx.x * 256 + t;
  uint32_t k = idx_arr[n];
  uint32_t r = atomicAdd(&h[k], 1u);
  __syncthreads();
  if (t < KMIX) base[t] = h[t] ? atomicAdd(&cursors[t], h[t]) : 0u;
  __syncthreads();
  sorted[base[k] + r] = (uint32_t)n;
}

// ---------- K4: per-bucket-chunk MFMA matvec batch ----------
__global__ __launch_bounds__(256) void k_main(
    const float* __restrict__ z, const float* __restrict__ means,
    const float* __restrict__ devs, const uint32_t* __restrict__ sorted,
    const uint32_t* __restrict__ counts, const uint32_t* __restrict__ offsets,
    float* __restrict__ out) {
  __shared__ uint32_t s_ent[CHUNK];
  __shared__ __align__(16) unsigned short s_devs[DD * 72];    // devs[k], bf16, stride 72
  __shared__ __align__(16) unsigned short s_x[CHUNK * 72];    // x rows, bf16, stride 72

  const int t = threadIdx.x;
  const int base = blockIdx.x * CHUNK;

  // which bucket does this chunk belong to? (offsets non-decreasing)
  int kb = 0;
  while (kb < KMIX - 1 && offsets[kb + 1] <= (uint32_t)base) ++kb;
  int nv = (int)counts[kb] - (base - (int)offsets[kb]);
  if (nv <= 0) return;                 // pure-padding chunk (uniform exit)
  if (nv > CHUNK) nv = CHUNK;

  if (t < CHUNK) s_ent[t] = (t < nv) ? sorted[base + t] : 0u;
  __syncthreads();

  // stage devs[kb] -> LDS bf16 (coalesced float4 reads, mostly L2 hits)
  {
    const float4* gd = reinterpret_cast<const float4*>(devs + (size_t)kb * DD * DD);
    #pragma unroll
    for (int it = 0; it < 4; ++it) {
      int e = t + it * 256;            // float4 index 0..1023
      float4 v = gd[e];
      int row = e >> 4, col = (e & 15) * 4;
      ushort4 w = make_ushort4(f2bf(v.x), f2bf(v.y), f2bf(v.z), f2bf(v.w));
      *reinterpret_cast<ushort4*>(&s_devs[row * 72 + col]) = w;
    }
  }
  // stage x rows -> LDS bf16 (one wave loads one row: 64 coalesced dwords)
  {
    int lane = t & 63, wr = t >> 6;
    #pragma unroll
    for (int rr = 0; rr < CHUNK; rr += 4) {
      int rl = rr + wr;
      uint32_t row = s_ent[rl];
      float xv = z[(size_t)row * ZS + 1 + lane];
      s_x[rl * 72 + lane] = f2bf(xv);
    }
  }
  __syncthreads();

  const int lane = t & 63, wave = t >> 6;
  const int m16 = lane & 15, quad = lane >> 4;

  float mv[4];
  #pragma unroll
  for (int it = 0; it < 4; ++it) mv[it] = means[kb * DD + it * 16 + m16];

  for (int g = wave; g < CHUNK / 16; g += 4) {
    // A operand: A[m=lane&15][k=quad*8+j] = x[row_m][k]
    const unsigned short* xr = &s_x[(g * 16 + m16) * 72 + quad * 8];
    bf16x8 a0 = *reinterpret_cast<const bf16x8*>(xr);
    bf16x8 a1 = *reinterpret_cast<const bf16x8*>(xr + 32);

    f32x4 acc[4];
    #pragma unroll
    for (int it = 0; it < 4; ++it) acc[it] = (f32x4){0.f, 0.f, 0.f, 0.f};

    #pragma unroll
    for (int it = 0; it < 4; ++it) {
      // B operand: B[k=quad*8+j][n=lane&15] = devs[itile*16+n][k]  (devs row contiguous)
      const unsigned short* dr = &s_devs[(it * 16 + m16) * 72 + quad * 8];
      bf16x8 b0 = *reinterpret_cast<const bf16x8*>(dr);
      bf16x8 b1 = *reinterpret_cast<const bf16x8*>(dr + 32);
      acc[it] = __builtin_amdgcn_mfma_f32_16x16x32_bf16(a0, b0, acc[it], 0, 0, 0);
      acc[it] = __builtin_amdgcn_mfma_f32_16x16x32_bf16(a1, b1, acc[it], 0, 0, 0);
    }

    // C/D layout: col = lane&15, row = quad*4 + reg
    #pragma unroll
    for (int reg = 0; reg < 4; ++reg) {
      int rp = g * 16 + quad * 4 + reg;
      if (rp < nv) {
        uint32_t row = s_ent[rp];
        float* orow = out + (size_t)row * DD + m16;
        #pragma unroll
        for (int it = 0; it < 4; ++it) orow[it * 16] = acc[it][reg] + mv[it];
      }
    }
  }
}

extern "C" void kernel_launch(void* const* d_in, const int* in_sizes, int n_in,
                              void* d_out, int out_size, void* d_ws, size_t ws_size,
                              hipStream_t stream) {
  const float* z     = (const float*)d_in[0];   // (N, 65)
  const float* means = (const float*)d_in[1];   // (64, 64)
  const float* devs  = (const float*)d_in[2];   // (64, 64, 64)
  const float* mix   = (const float*)d_in[3];   // (64,)
  float* out = (float*)d_out;

  uint32_t* W = (uint32_t*)d_ws;
  uint32_t* idx_arr = W;                               // NROWS
  uint32_t* bh      = idx_arr + NROWS;                 // (NROWS/256)*64
  uint32_t* counts  = bh + (NROWS / 256) * KMIX;       // 64
  uint32_t* offsets = counts + KMIX;                   // 65
  uint32_t* cursors = offsets + KMIX + 1;              // 64
  uint32_t* sorted  = cursors + KMIX;                  // PADN

  k_idx<<<NROWS / 256, 256, 0, stream>>>(z, mix, idx_arr, bh);
  k_scan<<<1, KMIX, 0, stream>>>(bh, counts, offsets, cursors);
  k_scatter<<<NROWS / 256, 256, 0, stream>>>(idx_arr, cursors, sorted);
  k_main<<<NBLK4, 256, 0, stream>>>(z, means, devs, sorted, counts, offsets, out);
}

// Round 2
// 94.796 us; speedup vs baseline: 1.0071x; 1.0071x over previous
//
#include <hip/hip_runtime.h>
#include <hip/hip_bf16.h>
#include <stdint.h>

#define NROWS 65536
#define KMIX 64
#define DD 64
#define ZS 65          // z row stride (u + 64 x)
#define CHUNK 128      // rows per k_main block; buckets padded to multiple of this
#define PADN (NROWS + KMIX * CHUNK)
#define NBLK4 (PADN / CHUNK)   // 576

typedef __bf16 bf16x8 __attribute__((ext_vector_type(8)));
typedef float f32x4 __attribute__((ext_vector_type(4)));

// fp32 -> bf16 bits, round-to-nearest-even (inputs finite)
__device__ __forceinline__ unsigned short f2bf(float f) {
  unsigned int x = __float_as_uint(f);
  unsigned int r = (x + 0x7FFFu + ((x >> 16) & 1u)) >> 16;
  return (unsigned short)r;
}

// padded exclusive scan of counts[64] into s_off[65]; call with t < 64 (wave 0)
__device__ __forceinline__ void scan_offsets(const uint32_t* __restrict__ counts,
                                             uint32_t* __restrict__ s_off, int t) {
  uint32_t c = counts[t];
  uint32_t p = ((c + CHUNK - 1) / CHUNK) * CHUNK;
  uint32_t inc = p;
  #pragma unroll
  for (int d = 1; d < 64; d <<= 1) {
    uint32_t v = __shfl_up(inc, d, 64);
    if (t >= d) inc += v;
  }
  s_off[t] = inc - p;
  if (t == 63) s_off[64] = inc;
}

// ---------- K1: idx per row + histogram -> global counts ----------
__global__ __launch_bounds__(256) void k_idx(
    const float* __restrict__ z, const float* __restrict__ mix,
    uint32_t* __restrict__ idx_arr, uint32_t* __restrict__ counts) {
  __shared__ float s_mix[KMIX];
  __shared__ uint32_t s_hist[KMIX];
  int t = threadIdx.x;
  if (t < KMIX) { s_mix[t] = mix[t]; s_hist[t] = 0u; }
  __syncthreads();
  int n = blockIdx.x * 256 + t;          // grid is exactly NROWS threads
  float u = z[n * ZS];
  int idx = 0;
  #pragma unroll
  for (int k = 0; k < KMIX; ++k) idx += (s_mix[k] <= u) ? 1 : 0;  // side='right'
  if (idx > KMIX - 1) idx = KMIX - 1;
  idx_arr[n] = (uint32_t)idx;
  atomicAdd(&s_hist[idx], 1u);
  __syncthreads();
  if (t < KMIX && s_hist[t]) atomicAdd(&counts[t], s_hist[t]);
}

// ---------- K2: scatter row ids into bucket segments ----------
__global__ __launch_bounds__(256) void k_scatter(
    const uint32_t* __restrict__ idx_arr, const uint32_t* __restrict__ counts,
    uint32_t* __restrict__ cursors, uint32_t* __restrict__ sorted) {
  __shared__ uint32_t s_off[KMIX + 1];
  __shared__ uint32_t h[KMIX];
  __shared__ uint32_t base[KMIX];
  int t = threadIdx.x;
  if (t < KMIX) { h[t] = 0u; scan_offsets(counts, s_off, t); }
  __syncthreads();
  int n = blockIdx.x * 256 + t;
  uint32_t k = idx_arr[n];
  uint32_t r = atomicAdd(&h[k], 1u);
  __syncthreads();
  if (t < KMIX) base[t] = s_off[t] + (h[t] ? atomicAdd(&cursors[t], h[t]) : 0u);
  __syncthreads();
  sorted[base[k] + r] = (uint32_t)n;
}

// ---------- K3: per-bucket-chunk MFMA matvec batch ----------
__global__ __launch_bounds__(256) void k_main(
    const float* __restrict__ z, const float* __restrict__ means,
    const float* __restrict__ devs, const uint32_t* __restrict__ sorted,
    const uint32_t* __restrict__ counts, float* __restrict__ out) {
  __shared__ uint32_t s_off[KMIX + 1];
  __shared__ uint32_t s_ent[CHUNK];
  __shared__ __align__(16) unsigned short s_devs[DD * 72];    // devs[k], bf16, stride 72
  __shared__ __align__(16) unsigned short s_x[CHUNK * 72];    // x rows, bf16, stride 72

  const int t = threadIdx.x;
  const int base = blockIdx.x * CHUNK;

  if (t < KMIX) scan_offsets(counts, s_off, t);
  __syncthreads();

  // which bucket does this chunk belong to? (s_off non-decreasing)
  int kb = 0;
  while (kb < KMIX - 1 && s_off[kb + 1] <= (uint32_t)base) ++kb;
  int nv = (int)counts[kb] - (base - (int)s_off[kb]);
  if (nv <= 0) return;                 // pure-padding chunk (uniform exit)
  if (nv > CHUNK) nv = CHUNK;

  if (t < CHUNK) s_ent[t] = (t < nv) ? sorted[base + t] : 0u;
  __syncthreads();

  // stage devs[kb] -> LDS bf16 (coalesced float4 reads, mostly L2 hits)
  {
    const float4* gd = reinterpret_cast<const float4*>(devs + (size_t)kb * DD * DD);
    #pragma unroll
    for (int it = 0; it < 4; ++it) {
      int e = t + it * 256;            // float4 index 0..1023
      float4 v = gd[e];
      int row = e >> 4, col = (e & 15) * 4;
      ushort4 w = make_ushort4(f2bf(v.x), f2bf(v.y), f2bf(v.z), f2bf(v.w));
      *reinterpret_cast<ushort4*>(&s_devs[row * 72 + col]) = w;
    }
  }
  // stage x rows -> LDS bf16 (one wave loads one row: 64 coalesced dwords)
  {
    int lane = t & 63, wr = t >> 6;
    #pragma unroll
    for (int rr = 0; rr < CHUNK; rr += 4) {
      int rl = rr + wr;
      uint32_t row = s_ent[rl];
      float xv = z[(size_t)row * ZS + 1 + lane];
      s_x[rl * 72 + lane] = f2bf(xv);
    }
  }
  __syncthreads();

  const int lane = t & 63, wave = t >> 6;
  const int m16 = lane & 15, quad = lane >> 4;

  float mv[4];
  #pragma unroll
  for (int it = 0; it < 4; ++it) mv[it] = means[kb * DD + it * 16 + m16];

  for (int g = wave; g < CHUNK / 16; g += 4) {
    // A operand: A[m=lane&15][k=quad*8+j] = x[row_m][k]
    const unsigned short* xr = &s_x[(g * 16 + m16) * 72 + quad * 8];
    bf16x8 a0 = *reinterpret_cast<const bf16x8*>(xr);
    bf16x8 a1 = *reinterpret_cast<const bf16x8*>(xr + 32);

    f32x4 acc[4];
    #pragma unroll
    for (int it = 0; it < 4; ++it) acc[it] = (f32x4){0.f, 0.f, 0.f, 0.f};

    #pragma unroll
    for (int it = 0; it < 4; ++it) {
      // B operand: B[k=quad*8+j][n=lane&15] = devs[itile*16+n][k]  (devs row contiguous)
      const unsigned short* dr = &s_devs[(it * 16 + m16) * 72 + quad * 8];
      bf16x8 b0 = *reinterpret_cast<const bf16x8*>(dr);
      bf16x8 b1 = *reinterpret_cast<const bf16x8*>(dr + 32);
      acc[it] = __builtin_amdgcn_mfma_f32_16x16x32_bf16(a0, b0, acc[it], 0, 0, 0);
      acc[it] = __builtin_amdgcn_mfma_f32_16x16x32_bf16(a1, b1, acc[it], 0, 0, 0);
    }

    // C/D layout: col = lane&15, row = quad*4 + reg
    #pragma unroll
    for (int reg = 0; reg < 4; ++reg) {
      int rp = g * 16 + quad * 4 + reg;
      if (rp < nv) {
        uint32_t row = s_ent[rp];
        float* orow = out + (size_t)row * DD + m16;
        #pragma unroll
        for (int it = 0; it < 4; ++it) orow[it * 16] = acc[it][reg] + mv[it];
      }
    }
  }
}

extern "C" void kernel_launch(void* const* d_in, const int* in_sizes, int n_in,
                              void* d_out, int out_size, void* d_ws, size_t ws_size,
                              hipStream_t stream) {
  const float* z     = (const float*)d_in[0];   // (N, 65)
  const float* means = (const float*)d_in[1];   // (64, 64)
  const float* devs  = (const float*)d_in[2];   // (64, 64, 64)
  const float* mix   = (const float*)d_in[3];   // (64,)
  float* out = (float*)d_out;

  uint32_t* W = (uint32_t*)d_ws;
  uint32_t* counts  = W;                         // 64
  uint32_t* cursors = counts + KMIX;             // 64
  uint32_t* idx_arr = cursors + KMIX;            // NROWS
  uint32_t* sorted  = idx_arr + NROWS;           // PADN

  // zero counts + cursors (ws is poisoned 0xAA by the harness)
  hipMemsetAsync(W, 0, 2 * KMIX * sizeof(uint32_t), stream);

  k_idx<<<NROWS / 256, 256, 0, stream>>>(z, mix, idx_arr, counts);
  k_scatter<<<NROWS / 256, 256, 0, stream>>>(idx_arr, counts, cursors, sorted);
  k_main<<<NBLK4, 256, 0, stream>>>(z, means, devs, sorted, counts, out);
}

// Round 3
// 92.827 us; speedup vs baseline: 1.0284x; 1.0212x over previous
//
#include <hip/hip_runtime.h>
#include <hip/hip_bf16.h>
#include <stdint.h>

#define NROWS 65536
#define KMIX 64
#define DD 64
#define ZS 65          // z row stride (u + 64 x)
#define CHUNK 128      // rows per k_main block; buckets padded to multiple of this
#define PADN (NROWS + KMIX * CHUNK)
#define NBLK4 (PADN / CHUNK)   // 576

typedef __bf16 bf16x8 __attribute__((ext_vector_type(8)));
typedef float f32x4 __attribute__((ext_vector_type(4)));

// fp32 -> bf16 bits, round-to-nearest-even (inputs finite)
__device__ __forceinline__ unsigned short f2bf(float f) {
  unsigned int x = __float_as_uint(f);
  unsigned int r = (x + 0x7FFFu + ((x >> 16) & 1u)) >> 16;
  return (unsigned short)r;
}

// padded exclusive scan of counts[64] into s_off[65]; call with t < 64 (wave 0)
__device__ __forceinline__ void scan_offsets(const uint32_t* __restrict__ counts,
                                             uint32_t* __restrict__ s_off, int t) {
  uint32_t c = counts[t];
  uint32_t p = ((c + CHUNK - 1) / CHUNK) * CHUNK;
  uint32_t inc = p;
  #pragma unroll
  for (int d = 1; d < 64; d <<= 1) {
    uint32_t v = __shfl_up(inc, d, 64);
    if (t >= d) inc += v;
  }
  s_off[t] = inc - p;
  if (t == 63) s_off[64] = inc;
}

// ---------- K1: idx per row + histogram -> global counts ----------
__global__ __launch_bounds__(256) void k_idx(
    const float* __restrict__ z, const float* __restrict__ mix,
    uint32_t* __restrict__ idx_arr, uint32_t* __restrict__ counts) {
  __shared__ float s_mix[KMIX];
  __shared__ uint32_t s_hist[KMIX];
  int t = threadIdx.x;
  if (t < KMIX) { s_mix[t] = mix[t]; s_hist[t] = 0u; }
  __syncthreads();
  int n = blockIdx.x * 256 + t;          // grid is exactly NROWS threads
  float u = z[n * ZS];
  int idx = 0;
  #pragma unroll
  for (int k = 0; k < KMIX; ++k) idx += (s_mix[k] <= u) ? 1 : 0;  // side='right'
  if (idx > KMIX - 1) idx = KMIX - 1;
  idx_arr[n] = (uint32_t)idx;
  atomicAdd(&s_hist[idx], 1u);
  __syncthreads();
  if (t < KMIX && s_hist[t]) atomicAdd(&counts[t], s_hist[t]);
}

// ---------- K2: scatter row ids into bucket segments ----------
__global__ __launch_bounds__(256) void k_scatter(
    const uint32_t* __restrict__ idx_arr, const uint32_t* __restrict__ counts,
    uint32_t* __restrict__ cursors, uint32_t* __restrict__ sorted) {
  __shared__ uint32_t s_off[KMIX + 1];
  __shared__ uint32_t h[KMIX];
  __shared__ uint32_t base[KMIX];
  int t = threadIdx.x;
  if (t < KMIX) { h[t] = 0u; scan_offsets(counts, s_off, t); }
  __syncthreads();
  int n = blockIdx.x * 256 + t;
  uint32_t k = idx_arr[n];
  uint32_t r = atomicAdd(&h[k], 1u);
  __syncthreads();
  if (t < KMIX) base[t] = s_off[t] + (h[t] ? atomicAdd(&cursors[t], h[t]) : 0u);
  __syncthreads();
  sorted[base[k] + r] = (uint32_t)n;
}

// ---------- K3: per-bucket-chunk MFMA matvec batch (512 threads / 8 waves) ----------
__global__ __launch_bounds__(512) void k_main(
    const float* __restrict__ z, const float* __restrict__ means,
    const float* __restrict__ devs, const uint32_t* __restrict__ sorted,
    const uint32_t* __restrict__ counts, float* __restrict__ out) {
  __shared__ uint32_t s_off[KMIX + 1];
  __shared__ uint32_t s_ent[CHUNK];
  __shared__ __align__(16) unsigned short s_devs[DD * 72];    // devs[k], bf16, stride 72
  __shared__ __align__(16) unsigned short s_x[CHUNK * 72];    // x rows, bf16, stride 72

  const int t = threadIdx.x;
  const int base = blockIdx.x * CHUNK;
  const int lane = t & 63, wave = t >> 6;

  if (t < KMIX) scan_offsets(counts, s_off, t);
  __syncthreads();

  // which bucket does this chunk belong to? (s_off non-decreasing, uniform loop)
  int kb = 0;
  while (kb < KMIX - 1 && s_off[kb + 1] <= (uint32_t)base) ++kb;
  int nv = (int)counts[kb] - (base - (int)s_off[kb]);
  if (nv <= 0) return;                 // pure-padding chunk (uniform exit)
  if (nv > CHUNK) nv = CHUNK;

  // s_ent for the store phase (consumed after the next barrier)
  if (t < CHUNK) s_ent[t] = (t < nv) ? sorted[base + t] : 0u;

  // stage devs[kb] -> LDS bf16 (coalesced float4 reads, mostly L2 hits)
  {
    const float4* gd = reinterpret_cast<const float4*>(devs + (size_t)kb * DD * DD);
    #pragma unroll
    for (int it = 0; it < 2; ++it) {
      int e = t + it * 512;            // float4 index 0..1023
      float4 v = gd[e];
      int row = e >> 4, col = (e & 15) * 4;
      ushort4 w = make_ushort4(f2bf(v.x), f2bf(v.y), f2bf(v.z), f2bf(v.w));
      *reinterpret_cast<ushort4*>(&s_devs[row * 72 + col]) = w;
    }
  }
  // stage x rows -> LDS bf16; row ids read straight from sorted[] (uniform -> s_load),
  // no dependency on the s_ent write above.
  {
    #pragma unroll
    for (int rr = 0; rr < CHUNK; rr += 8) {
      int rl = rr + wave;
      uint32_t row = (rl < nv) ? sorted[base + rl] : sorted[base];
      float xv = z[(size_t)row * ZS + 1 + lane];
      s_x[rl * 72 + lane] = f2bf(xv);
    }
  }
  __syncthreads();

  const int m16 = lane & 15, quad = lane >> 4;

  float mv[4];
  #pragma unroll
  for (int it = 0; it < 4; ++it) mv[it] = means[kb * DD + it * 16 + m16];

  {
    const int g = wave;   // 8 waves x 16 rows = CHUNK
    // A operand: A[m=lane&15][k=quad*8+j] = x[row_m][k]
    const unsigned short* xr = &s_x[(g * 16 + m16) * 72 + quad * 8];
    bf16x8 a0 = *reinterpret_cast<const bf16x8*>(xr);
    bf16x8 a1 = *reinterpret_cast<const bf16x8*>(xr + 32);

    f32x4 acc[4];
    #pragma unroll
    for (int it = 0; it < 4; ++it) acc[it] = (f32x4){0.f, 0.f, 0.f, 0.f};

    #pragma unroll
    for (int it = 0; it < 4; ++it) {
      // B operand: B[k=quad*8+j][n=lane&15] = devs[itile*16+n][k]  (devs row contiguous)
      const unsigned short* dr = &s_devs[(it * 16 + m16) * 72 + quad * 8];
      bf16x8 b0 = *reinterpret_cast<const bf16x8*>(dr);
      bf16x8 b1 = *reinterpret_cast<const bf16x8*>(dr + 32);
      acc[it] = __builtin_amdgcn_mfma_f32_16x16x32_bf16(a0, b0, acc[it], 0, 0, 0);
      acc[it] = __builtin_amdgcn_mfma_f32_16x16x32_bf16(a1, b1, acc[it], 0, 0, 0);
    }

    // C/D layout: col = lane&15, row = quad*4 + reg
    #pragma unroll
    for (int reg = 0; reg < 4; ++reg) {
      int rp = g * 16 + quad * 4 + reg;
      if (rp < nv) {
        uint32_t row = s_ent[rp];
        float* orow = out + (size_t)row * DD + m16;
        #pragma unroll
        for (int it = 0; it < 4; ++it) orow[it * 16] = acc[it][reg] + mv[it];
      }
    }
  }
}

extern "C" void kernel_launch(void* const* d_in, const int* in_sizes, int n_in,
                              void* d_out, int out_size, void* d_ws, size_t ws_size,
                              hipStream_t stream) {
  const float* z     = (const float*)d_in[0];   // (N, 65)
  const float* means = (const float*)d_in[1];   // (64, 64)
  const float* devs  = (const float*)d_in[2];   // (64, 64, 64)
  const float* mix   = (const float*)d_in[3];   // (64,)
  float* out = (float*)d_out;

  uint32_t* W = (uint32_t*)d_ws;
  uint32_t* counts  = W;                         // 64
  uint32_t* cursors = counts + KMIX;             // 64
  uint32_t* idx_arr = cursors + KMIX;            // NROWS
  uint32_t* sorted  = idx_arr + NROWS;           // PADN

  // zero counts + cursors (ws is poisoned 0xAA by the harness)
  hipMemsetAsync(W, 0, 2 * KMIX * sizeof(uint32_t), stream);

  k_idx<<<NROWS / 256, 256, 0, stream>>>(z, mix, idx_arr, counts);
  k_scatter<<<NROWS / 256, 256, 0, stream>>>(idx_arr, counts, cursors, sorted);
  k_main<<<NBLK4, 512, 0, stream>>>(z, means, devs, sorted, counts, out);
}